// Round 1
// baseline (3935.194 us; speedup 1.0000x reference)
//
#include <hip/hip_runtime.h>
#include <cstdint>
#include <cstddef>

// ---------------- problem constants ----------------
#define V_SZ 50257
#define H_SZ 512
#define S_SZ 128
#define NBEAM 5
#define TMAXX 32
#define TOK_SOS 1
#define TOK_EOS 2
#define NEGINF (-1e9f)

// ---------------- launch shape ----------------
#define GW 256            // decode workgroups: 1 per CU (was 128 -> half the chip idle)
#define NT 512
#define GENC 16           // encoder WGs (Whh register-resident)
#define COLS_PER_WG 197   // ceil(V/GW)

// ---------------- barrier ints (start of ws; first 8 KiB memset to 0) ----------------
#define BI_LEAF(l)  ((l)*32)        // 16 leaf counters (16 WGs each)
#define BI_ROOT     544
#define BI_REL(l)   (1024 + (l)*32) // 16 per-leaf release generations
#define BI_ECNT     1792
#define BI_EREL     1824

// ---------------- float region: fb = (float*)ws + 2048 ----------------
#define OF_GI    0            // 128*1536
#define OF_ENC   196608       // 128*512
#define OF_EW    262144       // 128*512  enc_out @ Wc_bottom
#define OF_H2    327680       // [2][5][512] ping-pong decoder hidden
#define OF_AL    332800       // [5][128] attention logits
#define OF_OTOP  333440       // [5][512] h2 @ Wc_top (flat b*512+j)
#define OF_PV    336000       // [256][5][5]
#define OF_PM    342400       // [256][5]
#define OF_PS    343680       // [256][5]
#define OF_SC    344960       // [8]
#define OI_BASE  344968
// int region (relative): pidx 0, tokA 6400, finA 6408, lenA 6416, parA 6424, seqA 6432 (+320)
#define I_TOK 6400
#define I_FIN 6408
#define I_LEN 6416
#define I_PAR 6424
#define I_SEQ 6432

template <typename T>
__device__ __forceinline__ T aload(const T* p){
  return __hip_atomic_load((T*)p, __ATOMIC_RELAXED, __HIP_MEMORY_SCOPE_AGENT);
}
template <typename T>
__device__ __forceinline__ void astore(T* p, T v){
  __hip_atomic_store(p, v, __ATOMIC_RELAXED, __HIP_MEMORY_SCOPE_AGENT);
}

__device__ __forceinline__ float wredsum(float a){
#pragma unroll
  for (int m = 32; m; m >>= 1) a += __shfl_xor(a, m, 64);
  return a;
}

// fence-free device barrier over GW WGs; last-arriving WG runs tail() before release.
template <typename F>
__device__ __forceinline__ void dbar(int* bi, int wid, F&& tail){
  __shared__ int s_last;
  int mygen = 0;
  __syncthreads();
  if (threadIdx.x == 0){
    int leaf = wid >> 4;
    mygen = aload(bi + BI_REL(leaf));
    __builtin_amdgcn_s_waitcnt(0);
    int lo = __hip_atomic_fetch_add(bi + BI_LEAF(leaf), 1, __ATOMIC_RELAXED, __HIP_MEMORY_SCOPE_AGENT);
    int last = 0;
    if (lo == 15){
      astore(bi + BI_LEAF(leaf), 0);
      __builtin_amdgcn_s_waitcnt(0);     // leaf reset at L3 before root arrive
      int ro = __hip_atomic_fetch_add(bi + BI_ROOT, 1, __ATOMIC_RELAXED, __HIP_MEMORY_SCOPE_AGENT);
      if (ro == (GW/16) - 1){
        astore(bi + BI_ROOT, 0);
        last = 1;
      }
    }
    if (!last){
      while (aload(bi + BI_REL(leaf)) == mygen) __builtin_amdgcn_s_sleep(4);
    }
    s_last = last;
  }
  __syncthreads();
  if (s_last){
    tail();
    __syncthreads();
    if (threadIdx.x == 0){
      __builtin_amdgcn_s_waitcnt(0);     // tail's sc1 stores + root reset at L3
#pragma unroll
      for (int l = 0; l < GW/16; ++l) astore(bi + BI_REL(l), mygen + 1);
    }
  }
  __syncthreads();
}

// ================= K1: gi = src_emb @ eWih^T + bih, plus beam-state init =================
__global__ __launch_bounds__(256)
void k_gi(const int* __restrict__ toks, const float* __restrict__ emb,
          const float* __restrict__ eWih, const float* __restrict__ ebih,
          float* __restrict__ ws)
{
  float* fb = ws + 2048;
  float* gi = fb + OF_GI;
  const int tid = threadIdx.x, wid = blockIdx.x, lane = tid & 63, wvi = tid >> 6;
  int Wg = wid*4 + wvi;                 // 0..1023
  for (int it = 0; it < 192; ++it){
    int idx = Wg*192 + it;              // covers 128*1536
    int s = idx / 1536, j = idx - s*1536;
    const float* er = emb + (size_t)toks[s]*H_SZ;
    const float* wr = eWih + (size_t)j*H_SZ;
    float a = 0.f;
#pragma unroll
    for (int u = 0; u < 8; ++u) a += er[u*64+lane]*wr[u*64+lane];
    a = wredsum(a);
    if (lane == 0) gi[idx] = a + ebih[j];
  }
  if (wid == 0){
    float* sc = fb + OF_SC;
    int* ib = (int*)(fb + OI_BASE);
    if (tid < NBEAM){
      sc[tid] = (tid==0) ? 0.f : NEGINF;
      ib[I_TOK+tid] = TOK_SOS; ib[I_FIN+tid] = 0; ib[I_LEN+tid] = 1; ib[I_PAR+tid] = 0;
    }
    for (int q = tid; q < 2*NBEAM*TMAXX; q += 256) ib[I_SEQ+q] = 0;
  }
}

// ================= K2: sequential encoder, 16 WGs, Whh in registers =================
__global__ __launch_bounds__(NT, 1)
void k_enc(const float* __restrict__ eWhh, const float* __restrict__ ebhh,
           float* __restrict__ ws)
{
  int* bi = (int*)ws;
  float* fb = ws + 2048;
  float* gi = fb + OF_GI;
  float* enc = fb + OF_ENC;
  const int tid = threadIdx.x, wid = blockIdx.x, lane = tid & 63, wvi = tid >> 6;
  const int i0 = wid*32;
  __shared__ float smF[96];

  // preload this wave's 12 Whh rows into registers (96 VGPRs/thread)
  float wreg[12][8];
#pragma unroll
  for (int dd = 0; dd < 12; ++dd){
    int d = wvi*12 + dd, g = d >> 5, il = d & 31;
    const float* wr = eWhh + (size_t)(g*512 + i0 + il)*H_SZ;
#pragma unroll
    for (int u = 0; u < 8; ++u) wreg[dd][u] = wr[u*64+lane];
  }

  for (int s = 0; s < S_SZ; ++s){
    float hreg[8];
    if (s == 0){
#pragma unroll
      for (int u = 0; u < 8; ++u) hreg[u] = 0.f;
    } else {
      const float* hp = enc + (size_t)(s-1)*H_SZ;
#pragma unroll
      for (int u = 0; u < 8; ++u) hreg[u] = aload(hp + u*64 + lane);
    }
#pragma unroll
    for (int dd = 0; dd < 12; ++dd){
      float a = 0.f;
#pragma unroll
      for (int u = 0; u < 8; ++u) a += wreg[dd][u]*hreg[u];
      a = wredsum(a);
      if (lane == 0) smF[wvi*12 + dd] = a;
    }
    __syncthreads();
    if (tid < 32){
      int i = i0 + tid;
      float gr = smF[tid], gz = smF[32+tid], gn = smF[64+tid];
      float gir = gi[s*1536 + i], giz = gi[s*1536 + 512 + i], gin = gi[s*1536 + 1024 + i];
      float hprev = (s==0) ? 0.f : aload(enc + (s-1)*H_SZ + i);
      float r = 1.f/(1.f + expf(-(gir + gr + ebhh[i])));
      float z = 1.f/(1.f + expf(-(giz + gz + ebhh[512+i])));
      float n = tanhf(gin + r*(gn + ebhh[1024+i]));
      astore(enc + s*H_SZ + i, (1.f - z)*n + z*hprev);
    }
    // fence-free 16-WG barrier
    __syncthreads();
    if (tid == 0){
      int g = aload(bi + BI_EREL);
      __builtin_amdgcn_s_waitcnt(0);
      int lo = __hip_atomic_fetch_add(bi + BI_ECNT, 1, __ATOMIC_RELAXED, __HIP_MEMORY_SCOPE_AGENT);
      if (lo == GENC - 1){
        astore(bi + BI_ECNT, 0);
        __builtin_amdgcn_s_waitcnt(0);
        astore(bi + BI_EREL, g + 1);
      } else {
        while (aload(bi + BI_EREL) == g) __builtin_amdgcn_s_sleep(2);
      }
    }
    __syncthreads();
  }
}

// ================= K3: EW = enc_out @ Wc_bottom =================
__global__ __launch_bounds__(NT)
void k_ew(const float* __restrict__ Wc, float* __restrict__ ws)
{
  float* fb = ws + 2048;
  float* enc = fb + OF_ENC;
  float* EW  = fb + OF_EW;
  const int tid = threadIdx.x, wid = blockIdx.x;
  int jc = wid & 15, sb = wid >> 4;
  int jl = tid & 31, sl = (tid >> 5) & 15;
  int s = sb*16 + sl, j = jc*32 + jl;
  const float* er = enc + (size_t)s*H_SZ;       // plain: kernel boundary made it visible
  const float* wc = Wc + (size_t)512*H_SZ;
  float a = 0.f;
  for (int k = 0; k < 512; ++k) a += er[k]*wc[(size_t)k*H_SZ + j];
  EW[s*H_SZ + j] = a;
}

// ================= K4: persistent decode, 256 WGs (1/CU), H-split vocab GEMM =================
__global__ __launch_bounds__(NT, 2)
void k_dec(const float* __restrict__ emb,
           const float* __restrict__ dWih, const float* __restrict__ dWhh,
           const float* __restrict__ dbih, const float* __restrict__ dbhh,
           const float* __restrict__ Wc,  const float* __restrict__ Wv,
           float* __restrict__ out, float* __restrict__ ws)
{
  const int wid = blockIdx.x, tid = threadIdx.x;
  const int lane = tid & 63, wvi = tid >> 6;
  int* bi = (int*)ws;
  float* fb = ws + 2048;
  float* enc  = fb + OF_ENC;
  float* EW   = fb + OF_EW;
  float* h2   = fb + OF_H2;
  float* al   = fb + OF_AL;
  float* otop = fb + OF_OTOP;
  float* pv   = fb + OF_PV;
  float* pm   = fb + OF_PM;
  float* ps   = fb + OF_PS;
  float* sc   = fb + OF_SC;
  int* ib   = (int*)(fb + OI_BASE);
  int* pidx = ib;
  int* tokA = ib + I_TOK;
  int* finA = ib + I_FIN;
  int* lenA = ib + I_LEN;
  int* parA = ib + I_PAR;
  int* seqA = ib + I_SEQ;   // [2][5][32]

  __shared__ float smF[1792];   // [0..511] small scratch, [512..1791] GEMM H-split partials
  __shared__ int   smI[256];
  __shared__ float s_buf[2560]; // stage A: h_prev rows; stage B: h2new; stage C: oo
  __shared__ float s_pp[648];   // softmax exp + sums

  // persistent decoder GRU weight rows: waves 0..5 hold 2 rows each, all 32 steps
  const int i0 = wid*2;
  float awreg[2][8];
  if (wvi < 6){
#pragma unroll
    for (int rr = 0; rr < 2; ++rr){
      int R = wvi*2 + rr;                 // 0..11
      int mat = R / 6, rem = R - mat*6;
      int g = rem >> 1, il = rem & 1;
      const float* wr = (mat ? dWhh : dWih) + (size_t)(g*512 + i0 + il)*H_SZ;
#pragma unroll
      for (int u = 0; u < 8; ++u) awreg[rr][u] = wr[u*64+lane];
    }
  }

  for (int t = 0; t < TMAXX; ++t){
    float* h2new = h2 + (t & 1)*2560;
    float* h2old = h2 + ((t & 1) ^ 1)*2560;

    // ---- Stage A: decoder GRU (2 hidden columns per WG) ----
    if (tid < NBEAM){ smI[tid] = aload(tokA + tid); smI[8 + tid] = t ? aload(parA + tid) : 0; }
    __syncthreads();
    if (t == 0){
      for (int q = tid; q < 2560; q += NT) s_buf[q] = enc[127*H_SZ + (q & 511)];
    } else {
      for (int q = tid; q < 2560; q += NT){
        int b = q >> 9;
        s_buf[q] = aload(h2old + smI[8 + b]*H_SZ + (q & 511));
      }
    }
    __syncthreads();
    if (wvi < 6){
      float srg[5][8];
      if (wvi < 3){                       // Wih side: x = emb[token]
#pragma unroll
        for (int b = 0; b < NBEAM; ++b){
          const float* sp = emb + (size_t)smI[b]*H_SZ;
#pragma unroll
          for (int u = 0; u < 8; ++u) srg[b][u] = sp[u*64+lane];
        }
      } else {                            // Whh side: h_prev
#pragma unroll
        for (int b = 0; b < NBEAM; ++b)
#pragma unroll
          for (int u = 0; u < 8; ++u) srg[b][u] = s_buf[b*512 + u*64 + lane];
      }
#pragma unroll
      for (int rr = 0; rr < 2; ++rr){
        int R = wvi*2 + rr;
#pragma unroll
        for (int b = 0; b < NBEAM; ++b){
          float a = 0.f;
#pragma unroll
          for (int u = 0; u < 8; ++u) a += awreg[rr][u]*srg[b][u];
          a = wredsum(a);
          if (lane == 0) smF[R*5 + b] = a;
        }
      }
    }
    __syncthreads();
    if (tid < 10){
      int b = tid >> 1, il = tid & 1;
      int i = i0 + il;
      float ir  = smF[(0  + il)*5 + b] + dbih[i];
      float iz  = smF[(2  + il)*5 + b] + dbih[512+i];
      float inn = smF[(4  + il)*5 + b] + dbih[1024+i];
      float hr  = smF[(6  + il)*5 + b] + dbhh[i];
      float hz  = smF[(8  + il)*5 + b] + dbhh[512+i];
      float hn  = smF[(10 + il)*5 + b] + dbhh[1024+i];
      float r = 1.f/(1.f + expf(-(ir + hr)));
      float z = 1.f/(1.f + expf(-(iz + hz)));
      float n = tanhf(inn + r*hn);
      float hp = s_buf[b*512 + i];
      astore(h2new + b*H_SZ + i, (1.f - z)*n + z*hp);
    }
    dbar(bi, wid, [&](){});

    // ---- Stage B: attention logits ((b,s) dots spread over 256 WGs x 3 waves) + otop ----
    for (int q = tid; q < 2560; q += NT) s_buf[q] = aload(h2new + q);
    __syncthreads();
    if (wvi < 3){
      int d = wvi*256 + wid;              // covers [0,640) exactly once
      if (d < 640){
        int b = d >> 7, s = d & 127;
        const float* er = enc + (size_t)s*H_SZ;
        float a = 0.f;
#pragma unroll
        for (int u = 0; u < 8; ++u) a += er[u*64+lane]*s_buf[b*512 + u*64 + lane];
        a = wredsum(a);
        if (lane == 0) astore(al + b*S_SZ + s, a);
      }
    }
    if (tid < 160){
      int q = tid % 10, ksl = tid / 10;
      int f = wid*10 + q;                 // flat b*512+j, 2560 total
      int b = f >> 9, j = f & 511;
      float a = 0.f;
#pragma unroll 8
      for (int u = 0; u < 32; ++u){
        int k = ksl*32 + u;
        a += s_buf[b*512 + k]*Wc[(size_t)k*H_SZ + j];
      }
      smF[q*16 + ksl] = a;
    }
    __syncthreads();
    if (tid < 10){
      float a = 0.f;
#pragma unroll
      for (int u = 0; u < 16; ++u) a += smF[tid*16 + u];
      astore(otop + wid*10 + tid, a);
    }
    dbar(bi, wid, [&](){});

    // ---- Stage C: softmax + o, H-split vocab GEMM, per-WG partials ----
    if (wvi < NBEAM){
      float a1 = aload(al + wvi*S_SZ + lane), a2 = aload(al + wvi*S_SZ + 64 + lane);
      float m = fmaxf(a1, a2);
#pragma unroll
      for (int mm = 32; mm; mm >>= 1) m = fmaxf(m, __shfl_xor(m, mm, 64));
      float e1 = expf(a1 - m), e2 = expf(a2 - m);
      s_pp[wvi*128 + lane] = e1; s_pp[wvi*128 + 64 + lane] = e2;
      float ssv = wredsum(e1 + e2);
      if (lane == 0) s_pp[640 + wvi] = ssv;
    }
    __syncthreads();
    {
      float acc[5] = {0.f,0.f,0.f,0.f,0.f};
      for (int s2 = 0; s2 < 128; ++s2){
        float e = EW[(size_t)s2*H_SZ + tid];
#pragma unroll
        for (int b = 0; b < NBEAM; ++b) acc[b] += e*s_pp[b*128 + s2];
      }
#pragma unroll
      for (int b = 0; b < NBEAM; ++b)
        s_buf[b*512 + tid] = tanhf(aload(otop + b*512 + tid) + acc[b]/s_pp[640 + b]);
    }
    __syncthreads();
    {
      // H-split: waves 0-3 (tid<256) rows 0..255, waves 4-7 rows 256..511 of same columns
      int half = tid >> 8;
      int c = tid & 255;
      int vbase = wid*COLS_PER_WG;
      int vv = vbase + c;
      bool act = (c < COLS_PER_WG) && (vv < V_SZ);
      int vc = act ? vv : vbase;
      const float* wp = Wv + (size_t)(half*256)*V_SZ + vc;
      const float* ob = s_buf + half*256;
      float a0=0.f,a1=0.f,a2=0.f,a3=0.f,a4=0.f;
      for (int hb = 0; hb < 256; hb += 32){
        float wr[32];
#pragma unroll
        for (int u = 0; u < 32; ++u) wr[u] = wp[(size_t)(hb+u)*V_SZ];
#pragma unroll
        for (int u = 0; u < 32; ++u){
          float w = wr[u]; int h = hb + u;
          a0 += w*ob[h];
          a1 += w*ob[512+h];
          a2 += w*ob[1024+h];
          a3 += w*ob[1536+h];
          a4 += w*ob[2048+h];
        }
      }
      float accs[5] = {a0,a1,a2,a3,a4};
      if (half){
#pragma unroll
        for (int b = 0; b < NBEAM; ++b) smF[512 + b*256 + c] = accs[b];
      }
      __syncthreads();
      if (!half){
#pragma unroll
        for (int b = 0; b < NBEAM; ++b) accs[b] += smF[512 + b*256 + c];
        if (!act){
#pragma unroll
          for (int b = 0; b < NBEAM; ++b) accs[b] = -3e38f;
        }
        int myv = act ? vv : 0x7FFFFFFF;
#pragma unroll
        for (int b = 0; b < NBEAM; ++b){
          float x = accs[b];
          float m = x;
#pragma unroll
          for (int mm = 32; mm; mm >>= 1) m = fmaxf(m, __shfl_xor(m, mm, 64));
          float e = expf(x - m);
          float ssum = wredsum(e);
          float bv = x; int bc = myv;
          float w5[5]; int i5[5];
#pragma unroll
          for (int r = 0; r < 5; ++r){
            float cv2 = bv; int ci2 = bc;
#pragma unroll
            for (int mm = 32; mm; mm >>= 1){
              float ov = __shfl_xor(cv2, mm, 64); int oi = __shfl_xor(ci2, mm, 64);
              bool take = (ov > cv2) || (ov == cv2 && oi < ci2);
              cv2 = take ? ov : cv2; ci2 = take ? oi : ci2;
            }
            w5[r] = cv2; i5[r] = ci2;
            if (bc == ci2) bv = -3e38f;
          }
          if (lane == 0){
#pragma unroll
            for (int r = 0; r < 5; ++r){ smF[(wvi*5+b)*5+r] = w5[r]; smI[(wvi*5+b)*5+r] = i5[r]; }
            smF[300 + wvi*5 + b] = m;
            smF[360 + wvi*5 + b] = ssum;
          }
        }
      }
      __syncthreads();
      if (tid < NBEAM){
        float M = -3.4e38f, Sv = 0.f;
#pragma unroll
        for (int w8 = 0; w8 < 4; ++w8){
          float m2 = smF[300 + w8*5 + tid], s2 = smF[360 + w8*5 + tid];
          if (m2 > M){ Sv = Sv*expf(M - m2) + s2; M = m2; }
          else       { Sv = Sv + s2*expf(m2 - M); }
        }
        astore(pm + wid*5 + tid, M); astore(ps + wid*5 + tid, Sv);
      }
      if (wvi < NBEAM){
        int b = wvi;
        float cval; int cidx;
        if (lane < 20){ cval = smF[((lane/5)*5 + b)*5 + (lane%5)]; cidx = smI[((lane/5)*5 + b)*5 + (lane%5)]; }
        else { cval = -3e38f; cidx = 0x7FFFFFFF; }
        float bv = cval; int bc = cidx;
#pragma unroll
        for (int r = 0; r < 5; ++r){
          float cv2 = bv; int ci2 = bc;
#pragma unroll
          for (int mm = 32; mm; mm >>= 1){
            float ov = __shfl_xor(cv2, mm, 64); int oi = __shfl_xor(ci2, mm, 64);
            bool take = (ov > cv2) || (ov == cv2 && oi < ci2);
            cv2 = take ? ov : cv2; ci2 = take ? oi : ci2;
          }
          if (lane == 0){ astore(pv + (wid*5+b)*5+r, cv2); astore(pidx + (wid*5+b)*5+r, ci2); }
          if (bc == ci2) bv = -3e38f;
        }
      }
    }
    dbar(bi, wid, [&](){
      // ======== Stage D (barrier tail, one WG): merge 4x64 WG groups ========
      int b5 = wvi;
      if (b5 < NBEAM){
        float M = aload(pm + lane*5 + b5), Sv = aload(ps + lane*5 + b5);
#pragma unroll
        for (int j = 1; j < GW/64; ++j){
          float m2 = aload(pm + (j*64+lane)*5 + b5), s2 = aload(ps + (j*64+lane)*5 + b5);
          if (m2 > M){ Sv = Sv*expf(M - m2) + s2; M = m2; }
          else       { Sv = Sv + s2*expf(m2 - M); }
        }
#pragma unroll
        for (int mm = 32; mm; mm >>= 1){
          float om = __shfl_xor(M, mm, 64), os = __shfl_xor(Sv, mm, 64);
          if (om > M){ Sv = Sv*expf(M - om) + os; M = om; }
          else       { Sv = Sv + os*expf(om - M); }
        }
        if (lane == 0){ smF[8 + b5] = M; smF[80 + b5] = logf(Sv); }
        float lv[5]; int li[5];
#pragma unroll
        for (int r = 0; r < 5; ++r){ lv[r] = aload(pv + (lane*5 + b5)*5 + r); li[r] = aload(pidx + (lane*5 + b5)*5 + r); }
        for (int j = 1; j < GW/64; ++j){
          for (int r = 0; r < 5; ++r){
            float nv = aload(pv + ((j*64+lane)*5 + b5)*5 + r); int ni = aload(pidx + ((j*64+lane)*5 + b5)*5 + r);
            bool ins = (nv > lv[4]) || (nv == lv[4] && ni < li[4]);
            if (!ins) break;
            lv[4] = nv; li[4] = ni;
#pragma unroll
            for (int p = 4; p > 0; --p){
              bool sw = (lv[p] > lv[p-1]) || (lv[p] == lv[p-1] && li[p] < li[p-1]);
              if (sw){ float tv = lv[p]; lv[p] = lv[p-1]; lv[p-1] = tv;
                       int ti = li[p]; li[p] = li[p-1]; li[p-1] = ti; }
            }
          }
        }
        float cv = lv[0]; int ci = li[0];
#pragma unroll
        for (int r = 0; r < 5; ++r){
          float xv = cv; int xi = ci;
#pragma unroll
          for (int mm = 32; mm; mm >>= 1){
            float ov = __shfl_xor(xv, mm, 64); int oi = __shfl_xor(xi, mm, 64);
            bool take = (ov > xv) || (ov == xv && oi < xi);
            xv = take ? ov : xv; xi = take ? oi : xi;
          }
          if (lane == 0){ smF[16 + b5*5 + r] = xv; smI[16 + b5*5 + r] = xi; }
          if (ci == xi){
            lv[0]=lv[1]; li[0]=li[1]; lv[1]=lv[2]; li[1]=li[2];
            lv[2]=lv[3]; li[2]=li[3]; lv[3]=lv[4]; li[3]=li[4];
            lv[4] = -3e38f; li[4] = 0x7FFFFFFF;
            cv = lv[0]; ci = li[0];
          }
        }
      }
      __syncthreads();
      if (wvi == 0){
        float cval = -3e38f; int cflat = 0x7FFFFFFF;
        int b = lane/5, k = lane - b*5;
        if (lane < 25){
          if (aload(finA + b)){
            if (k == 0){ cval = aload(sc + b) + 0.0f; cflat = b*V_SZ + TOK_EOS; }
          } else {
            cval = ((smF[16 + b*5 + k] - smF[8 + b]) - smF[80 + b]) + aload(sc + b);
            cflat = b*V_SZ + smI[16 + b*5 + k];
          }
        }
        float bv = cval; int bc = cflat;
#pragma unroll
        for (int r = 0; r < 5; ++r){
          float xv = bv; int xi = bc;
#pragma unroll
          for (int mm = 32; mm; mm >>= 1){
            float ov = __shfl_xor(xv, mm, 64); int oi = __shfl_xor(xi, mm, 64);
            bool take = (ov > xv) || (ov == xv && oi < xi);
            xv = take ? ov : xv; xi = take ? oi : xi;
          }
          if (lane == 0){ smF[48 + r] = xv; smI[48 + r] = xi; }
          if (bc == xi) bv = -3e38f;
        }
        if (lane < NBEAM){
          int r = lane;
          float nscore = smF[48 + r]; int nfl = smI[48 + r];
          int par = nfl / V_SZ; int tok = nfl - par*V_SZ;
          int ofin = aload(finA + par); int olen = aload(lenA + par);  // reads before writes (wave-lockstep)
          int nf = (ofin || tok == TOK_EOS) ? 1 : 0;
          int nl = olen + (ofin ? 0 : 1);
          astore(sc + r, nscore); astore(tokA + r, tok); astore(finA + r, nf);
          astore(lenA + r, nl); astore(parA + r, par);
          smI[56 + r] = par; smI[64 + r] = tok; smI[72 + r] = ofin; smI[80 + r] = nl;
          smF[56 + r] = nscore;
        }
      }
      __syncthreads();
      int cur = t & 1, nxt = 1 - cur;
      if (tid < 160){
        int r = tid >> 5, u = tid & 31;
        int par = smI[56 + r];
        int val = aload(seqA + cur*160 + par*32 + u);
        if (u == t) val = smI[72 + r] ? 0 : smI[64 + r];
        astore(seqA + nxt*160 + r*32 + u, val);
      }
      if (t == TMAXX - 1){
        __syncthreads();
        if (tid == 0){
          float nn[5];
#pragma unroll
          for (int r = 0; r < 5; ++r) nn[r] = smF[56 + r] / (float)smI[80 + r];
          int used = 0;
#pragma unroll
          for (int r = 0; r < 5; ++r){
            int best = -1;
            for (int q2 = 0; q2 < 5; ++q2){
              if (used & (1 << q2)) continue;
              if (best < 0 || nn[q2] > nn[best]) best = q2;
            }
            used |= (1 << best);
            smI[88 + r] = best; smF[64 + r] = nn[best];
          }
        }
        __syncthreads();
        if (tid < 160){
          int r = tid >> 5, u = tid & 31;
          int src = smI[88 + r];
          out[tid] = (float)aload(seqA + nxt*160 + src*32 + u);
        }
        if (tid >= 160 && tid < 165) out[tid] = smF[64 + (tid - 160)];
      }
    });
  }
}

extern "C" void kernel_launch(void* const* d_in, const int* in_sizes, int n_in,
                              void* d_out, int out_size, void* d_ws, size_t ws_size,
                              hipStream_t stream)
{
  (void)in_sizes; (void)n_in; (void)out_size; (void)ws_size;
  hipMemsetAsync(d_ws, 0, 8192, stream);   // barrier counters/generations
  float* ws = (float*)d_ws;
  k_gi<<<dim3(256), dim3(256), 0, stream>>>(
      (const int*)d_in[0], (const float*)d_in[1],
      (const float*)d_in[2], (const float*)d_in[4], ws);
  k_enc<<<dim3(GENC), dim3(NT), 0, stream>>>(
      (const float*)d_in[3], (const float*)d_in[5], ws);
  k_ew<<<dim3(128), dim3(NT), 0, stream>>>(
      (const float*)d_in[10], ws);
  k_dec<<<dim3(GW), dim3(NT), 0, stream>>>(
      (const float*)d_in[1],
      (const float*)d_in[6], (const float*)d_in[7],
      (const float*)d_in[8], (const float*)d_in[9],
      (const float*)d_in[10], (const float*)d_in[11],
      (float*)d_out, ws);
}